// Round 3
// baseline (407.820 us; speedup 1.0000x reference)
//
#include <hip/hip_runtime.h>

#define D 128
#define NG 64
#define NC 16
#define NEG 0.1f

// ---------- bf16 <-> fp32 helpers (bf16 stored as ushort, packed pairs in uint) ----------
__device__ __forceinline__ float bf2f(unsigned int u16) {
    union { unsigned int i; float f; } c;
    c.i = u16 << 16;
    return c.f;
}
__device__ __forceinline__ unsigned short f2bf(float f) {
    union { float f; unsigned int i; } c;
    c.f = f;
    unsigned int i = c.i;
    unsigned int r = (i + 0x7FFFu + ((i >> 16) & 1u)) >> 16;  // RNE
    return (unsigned short)r;
}

// ---------------- degree histogram ----------------
__global__ void deg_kernel(const int* __restrict__ dst, int* __restrict__ deg, int E) {
    int e = blockIdx.x * blockDim.x + threadIdx.x;
    if (e < E) atomicAdd(&deg[dst[e]], 1);
}

// ---------------- dinv = 1/sqrt(deg+1) ----------------
__global__ void dinv_kernel(const int* __restrict__ deg, float* __restrict__ dinv, int N) {
    int i = blockIdx.x * blockDim.x + threadIdx.x;
    if (i < N) dinv[i] = 1.0f / sqrtf((float)deg[i] + 1.0f);
}

// ---------------- 3-stage exclusive scan for CSR row pointers ----------------
__global__ void scan_block_kernel(const int* __restrict__ deg, int* __restrict__ scan1,
                                  int* __restrict__ blocksum, int N) {
    __shared__ int sm[256];
    int tid = threadIdx.x;
    int i = blockIdx.x * 256 + tid;
    int v = (i < N) ? deg[i] : 0;
    sm[tid] = v;
    __syncthreads();
    for (int off = 1; off < 256; off <<= 1) {
        int t = (tid >= off) ? sm[tid - off] : 0;
        __syncthreads();
        sm[tid] += t;
        __syncthreads();
    }
    if (i < N) scan1[i] = sm[tid];  // inclusive
    if (tid == 255) blocksum[blockIdx.x] = sm[255];
}

__global__ void scan_tops_kernel(const int* __restrict__ blocksum, int* __restrict__ blockoff,
                                 int nb) {
    __shared__ int sm[256];
    int tid = threadIdx.x;
    int v = (tid < nb) ? blocksum[tid] : 0;
    sm[tid] = v;
    __syncthreads();
    for (int off = 1; off < 256; off <<= 1) {
        int t = (tid >= off) ? sm[tid - off] : 0;
        __syncthreads();
        sm[tid] += t;
        __syncthreads();
    }
    blockoff[tid] = sm[tid] - v;  // exclusive
}

__global__ void finalize_ptr_kernel(const int* __restrict__ deg, const int* __restrict__ scan1,
                                    const int* __restrict__ blockoff, int* __restrict__ ptr,
                                    int N, int E) {
    int i = blockIdx.x * blockDim.x + threadIdx.x;
    if (i < N) {
        ptr[i] = scan1[i] - deg[i] + blockoff[i >> 8];  // exclusive prefix
        if (i == N - 1) ptr[N] = E;
    }
}

// ---------------- scatter edges into CSR by dst ----------------
__global__ void scatter_kernel(const int* __restrict__ src, const int* __restrict__ dst,
                               const int* __restrict__ ptr, int* __restrict__ fill,
                               int* __restrict__ csr_src, int E) {
    int e = blockIdx.x * blockDim.x + threadIdx.x;
    if (e < E) {
        int d = dst[e];
        int pos = ptr[d] + atomicAdd(&fill[d], 1);
        csr_src[pos] = src[e];
    }
}

// ============ GEMM variant 1: A fp32, W fp32, C packed-bf16 ============
// 64 rows/block, 256 threads; W-half + A-half staged in LDS (48 KB).
__global__ __launch_bounds__(256) void gemm_f32_kernel(const float* __restrict__ A,
                                                       const float* __restrict__ W,
                                                       unsigned int* __restrict__ C, int N) {
    __shared__ float Wl[64 * 128];  // 32 KB
    __shared__ float Al[64 * 64];   // 16 KB
    int tid = threadIdx.x;
    int rowstart = blockIdx.x * 64;
    int colbase = (tid & 31) * 4;
    int rowbase = (tid >> 5) * 8;

    float acc[8][4];
#pragma unroll
    for (int r = 0; r < 8; r++)
#pragma unroll
        for (int c = 0; c < 4; c++) acc[r][c] = 0.f;

    for (int p = 0; p < 2; ++p) {
        {
            const float4* Wv = (const float4*)(W + p * 64 * 128);
            float4* Wlv = (float4*)Wl;
#pragma unroll
            for (int i = 0; i < 8; i++) Wlv[tid + 256 * i] = Wv[tid + 256 * i];
        }
        {
            float4* Alv = (float4*)Al;
#pragma unroll
            for (int i = 0; i < 4; i++) {
                int li = tid + 256 * i;  // 0..1023
                int r = li >> 4;
                int c4 = li & 15;
                int row = rowstart + r;
                float4 v = make_float4(0.f, 0.f, 0.f, 0.f);
                if (row < N) v = *(const float4*)(A + (size_t)row * D + p * 64 + c4 * 4);
                Alv[li] = v;
            }
        }
        __syncthreads();

        for (int k = 0; k < 64; k += 4) {
            float4 w0 = *(const float4*)&Wl[(k + 0) * 128 + colbase];
            float4 w1 = *(const float4*)&Wl[(k + 1) * 128 + colbase];
            float4 w2 = *(const float4*)&Wl[(k + 2) * 128 + colbase];
            float4 w3 = *(const float4*)&Wl[(k + 3) * 128 + colbase];
#pragma unroll
            for (int r = 0; r < 8; r++) {
                float4 a = *(const float4*)&Al[(rowbase + r) * 64 + k];
                acc[r][0] += a.x * w0.x; acc[r][1] += a.x * w0.y; acc[r][2] += a.x * w0.z; acc[r][3] += a.x * w0.w;
                acc[r][0] += a.y * w1.x; acc[r][1] += a.y * w1.y; acc[r][2] += a.y * w1.z; acc[r][3] += a.y * w1.w;
                acc[r][0] += a.z * w2.x; acc[r][1] += a.z * w2.y; acc[r][2] += a.z * w2.z; acc[r][3] += a.z * w2.w;
                acc[r][0] += a.w * w3.x; acc[r][1] += a.w * w3.y; acc[r][2] += a.w * w3.z; acc[r][3] += a.w * w3.w;
            }
        }
        __syncthreads();
    }

#pragma unroll
    for (int r = 0; r < 8; r++) {
        int row = rowstart + rowbase + r;
        if (row < N) {
            uint2 v;
            v.x = (unsigned int)f2bf(acc[r][0]) | ((unsigned int)f2bf(acc[r][1]) << 16);
            v.y = (unsigned int)f2bf(acc[r][2]) | ((unsigned int)f2bf(acc[r][3]) << 16);
            *(uint2*)(C + (size_t)row * 64 + colbase / 2) = v;
        }
    }
}

// ============ GEMM variant 2: A packed-bf16, W fp32, C packed-bf16 ============
__global__ __launch_bounds__(256) void gemm_bf16_kernel(const unsigned int* __restrict__ A,
                                                        const float* __restrict__ W,
                                                        unsigned int* __restrict__ C, int N) {
    __shared__ float Wl[64 * 128];  // 32 KB
    __shared__ float Al[64 * 64];   // 16 KB
    int tid = threadIdx.x;
    int rowstart = blockIdx.x * 64;
    int colbase = (tid & 31) * 4;
    int rowbase = (tid >> 5) * 8;

    float acc[8][4];
#pragma unroll
    for (int r = 0; r < 8; r++)
#pragma unroll
        for (int c = 0; c < 4; c++) acc[r][c] = 0.f;

    for (int p = 0; p < 2; ++p) {
        {
            const float4* Wv = (const float4*)(W + p * 64 * 128);
            float4* Wlv = (float4*)Wl;
#pragma unroll
            for (int i = 0; i < 8; i++) Wlv[tid + 256 * i] = Wv[tid + 256 * i];
        }
        {
#pragma unroll
            for (int i = 0; i < 4; i++) {
                int li = tid + 256 * i;  // 0..1023
                int r = li >> 4;
                int c4 = li & 15;       // 4-element chunk within 64-col half
                int row = rowstart + r;
                uint2 a = make_uint2(0u, 0u);
                if (row < N) a = *(const uint2*)(A + (size_t)row * 64 + p * 32 + c4 * 2);
                int base = r * 64 + c4 * 4;
                Al[base + 0] = bf2f(a.x & 0xffffu);
                Al[base + 1] = bf2f(a.x >> 16);
                Al[base + 2] = bf2f(a.y & 0xffffu);
                Al[base + 3] = bf2f(a.y >> 16);
            }
        }
        __syncthreads();

        for (int k = 0; k < 64; k += 4) {
            float4 w0 = *(const float4*)&Wl[(k + 0) * 128 + colbase];
            float4 w1 = *(const float4*)&Wl[(k + 1) * 128 + colbase];
            float4 w2 = *(const float4*)&Wl[(k + 2) * 128 + colbase];
            float4 w3 = *(const float4*)&Wl[(k + 3) * 128 + colbase];
#pragma unroll
            for (int r = 0; r < 8; r++) {
                float4 a = *(const float4*)&Al[(rowbase + r) * 64 + k];
                acc[r][0] += a.x * w0.x; acc[r][1] += a.x * w0.y; acc[r][2] += a.x * w0.z; acc[r][3] += a.x * w0.w;
                acc[r][0] += a.y * w1.x; acc[r][1] += a.y * w1.y; acc[r][2] += a.y * w1.z; acc[r][3] += a.y * w1.w;
                acc[r][0] += a.z * w2.x; acc[r][1] += a.z * w2.y; acc[r][2] += a.z * w2.z; acc[r][3] += a.z * w2.w;
                acc[r][0] += a.w * w3.x; acc[r][1] += a.w * w3.y; acc[r][2] += a.w * w3.z; acc[r][3] += a.w * w3.w;
            }
        }
        __syncthreads();
    }

#pragma unroll
    for (int r = 0; r < 8; r++) {
        int row = rowstart + rowbase + r;
        if (row < N) {
            uint2 v;
            v.x = (unsigned int)f2bf(acc[r][0]) | ((unsigned int)f2bf(acc[r][1]) << 16);
            v.y = (unsigned int)f2bf(acc[r][2]) | ((unsigned int)f2bf(acc[r][3]) << 16);
            *(uint2*)(C + (size_t)row * 64 + colbase / 2) = v;
        }
    }
}

// ---------------- gather + self-loop + bias + leaky_relu ----------------
// one wave (64 lanes) per node; each lane owns 2 features (one packed uint).
__global__ void combine_kernel(const unsigned int* __restrict__ h, const int* __restrict__ ptr,
                               const int* __restrict__ csr_src, const float* __restrict__ dinv,
                               const float* __restrict__ b,
                               unsigned int* __restrict__ out, int N) {
    int wave = threadIdx.x >> 6;
    int lane = threadIdx.x & 63;
    int i = blockIdx.x * 4 + wave;
    if (i >= N) return;
    float di = dinv[i];
    int lo = ptr[i], hi = ptr[i + 1];
    float a0 = 0.f, a1 = 0.f;
    for (int e = lo; e < hi; ++e) {
        int s = csr_src[e];
        float c = dinv[s] * di;
        unsigned int v = h[(size_t)s * 64 + lane];
        a0 += bf2f(v & 0xffffu) * c;
        a1 += bf2f(v >> 16) * c;
    }
    unsigned int sv = h[(size_t)i * 64 + lane];
    float2 bv = ((const float2*)b)[lane];
    float dd = di * di;
    float v0 = a0 + bf2f(sv & 0xffffu) * dd + bv.x;
    float v1 = a1 + bf2f(sv >> 16) * dd + bv.y;
    v0 = (v0 >= 0.f) ? v0 : NEG * v0;
    v1 = (v1 >= 0.f) ? v1 : NEG * v1;
    out[(size_t)i * 64 + lane] = (unsigned int)f2bf(v0) | ((unsigned int)f2bf(v1) << 16);
}

// ---------------- global mean pool (batch sorted, intermediates bf16) ----------------
__global__ void pool_kernel(const unsigned int* __restrict__ a2, const int* __restrict__ batch,
                            float* __restrict__ pooled, int N) {
    int g = blockIdx.x;
    int lo, hi;
    {
        int l = 0, h = N;
        while (l < h) { int m = (l + h) >> 1; if (batch[m] < g) l = m + 1; else h = m; }
        lo = l;
        l = lo; h = N;
        while (l < h) { int m = (l + h) >> 1; if (batch[m] < g + 1) l = m + 1; else h = m; }
        hi = l;
    }
    int lane = threadIdx.x & 63;
    int quarter = threadIdx.x >> 6;  // block = 256 -> 4 waves
    float s0 = 0.f, s1 = 0.f;
    for (int r = lo + quarter; r < hi; r += 4) {
        unsigned int v = a2[(size_t)r * 64 + lane];
        s0 += bf2f(v & 0xffffu);
        s1 += bf2f(v >> 16);
    }
    __shared__ float sm0[256];
    __shared__ float sm1[256];
    sm0[threadIdx.x] = s0;
    sm1[threadIdx.x] = s1;
    __syncthreads();
    if (quarter == 0) {
        float t0 = sm0[lane] + sm0[lane + 64] + sm0[lane + 128] + sm0[lane + 192];
        float t1 = sm1[lane] + sm1[lane + 64] + sm1[lane + 128] + sm1[lane + 192];
        int cnt = hi - lo;
        float inv = 1.0f / (float)(cnt > 0 ? cnt : 1);
        pooled[g * D + 2 * lane] = t0 * inv;
        pooled[g * D + 2 * lane + 1] = t1 * inv;
    }
}

// ---------------- final linear [64,128] @ [128,16] + bl (all fp32) ----------------
__global__ void final_kernel(const float* __restrict__ pooled, const float* __restrict__ Wl,
                             const float* __restrict__ bl, float* __restrict__ out) {
    int t = blockIdx.x * blockDim.x + threadIdx.x;
    if (t >= NG * NC) return;
    int g = t >> 4, c = t & 15;
    float acc = bl[c];
    for (int k = 0; k < D; k++) acc += pooled[g * D + k] * Wl[k * NC + c];
    out[t] = acc;
}

extern "C" void kernel_launch(void* const* d_in, const int* in_sizes, int n_in,
                              void* d_out, int out_size, void* d_ws, size_t ws_size,
                              hipStream_t stream) {
    const float* x = (const float*)d_in[0];
    const int* ei = (const int*)d_in[1];
    const int* batch = (const int*)d_in[2];
    const float* W1 = (const float*)d_in[3];
    const float* b1 = (const float*)d_in[4];
    const float* W2 = (const float*)d_in[5];
    const float* b2 = (const float*)d_in[6];
    const float* Wlin = (const float*)d_in[7];
    const float* bl = (const float*)d_in[8];
    float* out = (float*)d_out;

    int N = in_sizes[0] / D;
    int E = in_sizes[1] / 2;
    const int* src = ei;
    const int* dst = ei + E;

    // workspace layout (float units; intermediates are packed-bf16 to stay < ~29 MB)
    float* ws = (float*)d_ws;
    size_t o = 0;
    unsigned int* bufA = (unsigned int*)(ws + o); o += (size_t)N * 64;  // 12.8 MB (N x 128 bf16)
    unsigned int* bufB = (unsigned int*)(ws + o); o += (size_t)N * 64;  // 12.8 MB
    int* deg = (int*)(ws + o);      o += N;       // zeroed below
    int* fill = (int*)(ws + o);     o += N;       // zeroed below (adjacent to deg)
    float* dinv = ws + o;           o += N;
    int* scan1 = (int*)(ws + o);    o += N;
    int* blocksum = (int*)(ws + o); o += 256;
    int* blockoff = (int*)(ws + o); o += 256;
    int* csr_ptr = (int*)(ws + o);  o += (N + 4);
    int* csr_src = (int*)(ws + o);  o += E;
    float* pooled = ws + o;         o += NG * D;

    hipMemsetAsync(deg, 0, (size_t)2 * N * sizeof(int), stream);  // deg + fill

    int tb = 256;
    int nscan = (N + 255) / 256;
    deg_kernel<<<(E + tb - 1) / tb, tb, 0, stream>>>(dst, deg, E);
    dinv_kernel<<<(N + tb - 1) / tb, tb, 0, stream>>>(deg, dinv, N);
    scan_block_kernel<<<nscan, 256, 0, stream>>>(deg, scan1, blocksum, N);
    scan_tops_kernel<<<1, 256, 0, stream>>>(blocksum, blockoff, nscan);
    finalize_ptr_kernel<<<nscan, 256, 0, stream>>>(deg, scan1, blockoff, csr_ptr, N, E);
    scatter_kernel<<<(E + tb - 1) / tb, tb, 0, stream>>>(src, dst, csr_ptr, fill, csr_src, E);

    int gblocks = (N + 63) / 64;
    int cblocks = (N + 3) / 4;
    // layer 1
    gemm_f32_kernel<<<gblocks, 256, 0, stream>>>(x, W1, bufA, N);
    combine_kernel<<<cblocks, 256, 0, stream>>>(bufA, csr_ptr, csr_src, dinv, b1, bufB, N);
    // layer 2
    gemm_bf16_kernel<<<gblocks, 256, 0, stream>>>(bufB, W2, bufA, N);
    combine_kernel<<<cblocks, 256, 0, stream>>>(bufA, csr_ptr, csr_src, dinv, b2, bufB, N);
    // pool + classifier
    pool_kernel<<<NG, 256, 0, stream>>>(bufB, batch, pooled, N);
    final_kernel<<<(NG * NC + tb - 1) / tb, tb, 0, stream>>>(pooled, Wlin, bl, out);
}

// Round 4
// 304.602 us; speedup vs baseline: 1.3389x; 1.3389x over previous
//
#include <hip/hip_runtime.h>

#define D 128
#define NG 64
#define NC 16
#define NEG 0.1f

// ---------- bf16 <-> fp32 helpers (bf16 stored as ushort, packed pairs in uint) ----------
__device__ __forceinline__ float bf2f(unsigned int u16) {
    union { unsigned int i; float f; } c;
    c.i = u16 << 16;
    return c.f;
}
__device__ __forceinline__ unsigned short f2bf(float f) {
    union { float f; unsigned int i; } c;
    c.f = f;
    unsigned int i = c.i;
    unsigned int r = (i + 0x7FFFu + ((i >> 16) & 1u)) >> 16;  // RNE
    return (unsigned short)r;
}

// ---------------- degree histogram ----------------
__global__ void deg_kernel(const int* __restrict__ dst, int* __restrict__ deg, int E) {
    int e = blockIdx.x * blockDim.x + threadIdx.x;
    if (e < E) atomicAdd(&deg[dst[e]], 1);
}

// ---------------- dinv = 1/sqrt(deg+1) ----------------
__global__ void dinv_kernel(const int* __restrict__ deg, float* __restrict__ dinv, int N) {
    int i = blockIdx.x * blockDim.x + threadIdx.x;
    if (i < N) dinv[i] = 1.0f / sqrtf((float)deg[i] + 1.0f);
}

// ---------------- 3-stage exclusive scan for CSR row pointers ----------------
__global__ void scan_block_kernel(const int* __restrict__ deg, int* __restrict__ scan1,
                                  int* __restrict__ blocksum, int N) {
    __shared__ int sm[256];
    int tid = threadIdx.x;
    int i = blockIdx.x * 256 + tid;
    int v = (i < N) ? deg[i] : 0;
    sm[tid] = v;
    __syncthreads();
    for (int off = 1; off < 256; off <<= 1) {
        int t = (tid >= off) ? sm[tid - off] : 0;
        __syncthreads();
        sm[tid] += t;
        __syncthreads();
    }
    if (i < N) scan1[i] = sm[tid];  // inclusive
    if (tid == 255) blocksum[blockIdx.x] = sm[255];
}

__global__ void scan_tops_kernel(const int* __restrict__ blocksum, int* __restrict__ blockoff,
                                 int nb) {
    __shared__ int sm[256];
    int tid = threadIdx.x;
    int v = (tid < nb) ? blocksum[tid] : 0;
    sm[tid] = v;
    __syncthreads();
    for (int off = 1; off < 256; off <<= 1) {
        int t = (tid >= off) ? sm[tid - off] : 0;
        __syncthreads();
        sm[tid] += t;
        __syncthreads();
    }
    blockoff[tid] = sm[tid] - v;  // exclusive
}

__global__ void finalize_ptr_kernel(const int* __restrict__ deg, const int* __restrict__ scan1,
                                    const int* __restrict__ blockoff, int* __restrict__ ptr,
                                    int N, int E) {
    int i = blockIdx.x * blockDim.x + threadIdx.x;
    if (i < N) {
        ptr[i] = scan1[i] - deg[i] + blockoff[i >> 8];  // exclusive prefix
        if (i == N - 1) ptr[N] = E;
    }
}

// ---------------- scatter edges into CSR by dst ----------------
__global__ void scatter_kernel(const int* __restrict__ src, const int* __restrict__ dst,
                               const int* __restrict__ ptr, int* __restrict__ fill,
                               int* __restrict__ csr_src, int E) {
    int e = blockIdx.x * blockDim.x + threadIdx.x;
    if (e < E) {
        int d = dst[e];
        int pos = ptr[d] + atomicAdd(&fill[d], 1);
        csr_src[pos] = src[e];
    }
}

// ============ GEMM variant 1: A fp32, W fp32, C packed-bf16 ============
__global__ __launch_bounds__(256) void gemm_f32_kernel(const float* __restrict__ A,
                                                       const float* __restrict__ W,
                                                       unsigned int* __restrict__ C, int N) {
    __shared__ float Wl[64 * 128];  // 32 KB
    __shared__ float Al[64 * 64];   // 16 KB
    int tid = threadIdx.x;
    int rowstart = blockIdx.x * 64;
    int colbase = (tid & 31) * 4;
    int rowbase = (tid >> 5) * 8;

    float acc[8][4];
#pragma unroll
    for (int r = 0; r < 8; r++)
#pragma unroll
        for (int c = 0; c < 4; c++) acc[r][c] = 0.f;

    for (int p = 0; p < 2; ++p) {
        {
            const float4* Wv = (const float4*)(W + p * 64 * 128);
            float4* Wlv = (float4*)Wl;
#pragma unroll
            for (int i = 0; i < 8; i++) Wlv[tid + 256 * i] = Wv[tid + 256 * i];
        }
        {
            float4* Alv = (float4*)Al;
#pragma unroll
            for (int i = 0; i < 4; i++) {
                int li = tid + 256 * i;  // 0..1023
                int r = li >> 4;
                int c4 = li & 15;
                int row = rowstart + r;
                float4 v = make_float4(0.f, 0.f, 0.f, 0.f);
                if (row < N) v = *(const float4*)(A + (size_t)row * D + p * 64 + c4 * 4);
                Alv[li] = v;
            }
        }
        __syncthreads();

        for (int k = 0; k < 64; k += 4) {
            float4 w0 = *(const float4*)&Wl[(k + 0) * 128 + colbase];
            float4 w1 = *(const float4*)&Wl[(k + 1) * 128 + colbase];
            float4 w2 = *(const float4*)&Wl[(k + 2) * 128 + colbase];
            float4 w3 = *(const float4*)&Wl[(k + 3) * 128 + colbase];
#pragma unroll
            for (int r = 0; r < 8; r++) {
                float4 a = *(const float4*)&Al[(rowbase + r) * 64 + k];
                acc[r][0] += a.x * w0.x; acc[r][1] += a.x * w0.y; acc[r][2] += a.x * w0.z; acc[r][3] += a.x * w0.w;
                acc[r][0] += a.y * w1.x; acc[r][1] += a.y * w1.y; acc[r][2] += a.y * w1.z; acc[r][3] += a.y * w1.w;
                acc[r][0] += a.z * w2.x; acc[r][1] += a.z * w2.y; acc[r][2] += a.z * w2.z; acc[r][3] += a.z * w2.w;
                acc[r][0] += a.w * w3.x; acc[r][1] += a.w * w3.y; acc[r][2] += a.w * w3.z; acc[r][3] += a.w * w3.w;
            }
        }
        __syncthreads();
    }

#pragma unroll
    for (int r = 0; r < 8; r++) {
        int row = rowstart + rowbase + r;
        if (row < N) {
            uint2 v;
            v.x = (unsigned int)f2bf(acc[r][0]) | ((unsigned int)f2bf(acc[r][1]) << 16);
            v.y = (unsigned int)f2bf(acc[r][2]) | ((unsigned int)f2bf(acc[r][3]) << 16);
            *(uint2*)(C + (size_t)row * 64 + colbase / 2) = v;
        }
    }
}

// ============ GEMM variant 2: A packed-bf16, W fp32, C packed-bf16 ============
__global__ __launch_bounds__(256) void gemm_bf16_kernel(const unsigned int* __restrict__ A,
                                                        const float* __restrict__ W,
                                                        unsigned int* __restrict__ C, int N) {
    __shared__ float Wl[64 * 128];  // 32 KB
    __shared__ float Al[64 * 64];   // 16 KB
    int tid = threadIdx.x;
    int rowstart = blockIdx.x * 64;
    int colbase = (tid & 31) * 4;
    int rowbase = (tid >> 5) * 8;

    float acc[8][4];
#pragma unroll
    for (int r = 0; r < 8; r++)
#pragma unroll
        for (int c = 0; c < 4; c++) acc[r][c] = 0.f;

    for (int p = 0; p < 2; ++p) {
        {
            const float4* Wv = (const float4*)(W + p * 64 * 128);
            float4* Wlv = (float4*)Wl;
#pragma unroll
            for (int i = 0; i < 8; i++) Wlv[tid + 256 * i] = Wv[tid + 256 * i];
        }
        {
#pragma unroll
            for (int i = 0; i < 4; i++) {
                int li = tid + 256 * i;  // 0..1023
                int r = li >> 4;
                int c4 = li & 15;
                int row = rowstart + r;
                uint2 a = make_uint2(0u, 0u);
                if (row < N) a = *(const uint2*)(A + (size_t)row * 64 + p * 32 + c4 * 2);
                int base = r * 64 + c4 * 4;
                Al[base + 0] = bf2f(a.x & 0xffffu);
                Al[base + 1] = bf2f(a.x >> 16);
                Al[base + 2] = bf2f(a.y & 0xffffu);
                Al[base + 3] = bf2f(a.y >> 16);
            }
        }
        __syncthreads();

        for (int k = 0; k < 64; k += 4) {
            float4 w0 = *(const float4*)&Wl[(k + 0) * 128 + colbase];
            float4 w1 = *(const float4*)&Wl[(k + 1) * 128 + colbase];
            float4 w2 = *(const float4*)&Wl[(k + 2) * 128 + colbase];
            float4 w3 = *(const float4*)&Wl[(k + 3) * 128 + colbase];
#pragma unroll
            for (int r = 0; r < 8; r++) {
                float4 a = *(const float4*)&Al[(rowbase + r) * 64 + k];
                acc[r][0] += a.x * w0.x; acc[r][1] += a.x * w0.y; acc[r][2] += a.x * w0.z; acc[r][3] += a.x * w0.w;
                acc[r][0] += a.y * w1.x; acc[r][1] += a.y * w1.y; acc[r][2] += a.y * w1.z; acc[r][3] += a.y * w1.w;
                acc[r][0] += a.z * w2.x; acc[r][1] += a.z * w2.y; acc[r][2] += a.z * w2.z; acc[r][3] += a.z * w2.w;
                acc[r][0] += a.w * w3.x; acc[r][1] += a.w * w3.y; acc[r][2] += a.w * w3.z; acc[r][3] += a.w * w3.w;
            }
        }
        __syncthreads();
    }

#pragma unroll
    for (int r = 0; r < 8; r++) {
        int row = rowstart + rowbase + r;
        if (row < N) {
            uint2 v;
            v.x = (unsigned int)f2bf(acc[r][0]) | ((unsigned int)f2bf(acc[r][1]) << 16);
            v.y = (unsigned int)f2bf(acc[r][2]) | ((unsigned int)f2bf(acc[r][3]) << 16);
            *(uint2*)(C + (size_t)row * 64 + colbase / 2) = v;
        }
    }
}

// ---------------- gather + self-loop + bias + leaky_relu ----------------
// one wave per node; uint4 loads (8 feats/lane), 16 lanes/row -> 4 neighbor rows in flight.
__global__ void combine_kernel(const uint4* __restrict__ h4, const int* __restrict__ ptr,
                               const int* __restrict__ csr_src, const float* __restrict__ dinv,
                               const float* __restrict__ b,
                               uint4* __restrict__ out4, int N) {
    int wave = threadIdx.x >> 6;
    int lane = threadIdx.x & 63;
    int i = blockIdx.x * 4 + wave;
    if (i >= N) return;
    int q = lane >> 4;     // quarter: which of 4 rows in flight
    int l16 = lane & 15;   // uint4 index within row (row = 16 x uint4)

    float di = dinv[i];
    int lo = ptr[i], hi = ptr[i + 1];
    int deg = hi - lo;

    float a0 = 0.f, a1 = 0.f, a2 = 0.f, a3 = 0.f, a4 = 0.f, a5 = 0.f, a6 = 0.f, a7 = 0.f;

    for (int base = 0; base < deg; base += 64) {
        int j = base + lane;
        int idx = 0;
        float c = 0.f;
        if (j < deg) {
            idx = csr_src[lo + j];
            c = dinv[idx] * di;
        }
        int cnt = min(64, deg - base);
        for (int jj = q; jj < cnt; jj += 4) {
            int s = __shfl(idx, jj);
            float coef = __shfl(c, jj);
            uint4 v = h4[(size_t)s * 16 + l16];
            a0 += bf2f(v.x & 0xffffu) * coef;
            a1 += bf2f(v.x >> 16) * coef;
            a2 += bf2f(v.y & 0xffffu) * coef;
            a3 += bf2f(v.y >> 16) * coef;
            a4 += bf2f(v.z & 0xffffu) * coef;
            a5 += bf2f(v.z >> 16) * coef;
            a6 += bf2f(v.w & 0xffffu) * coef;
            a7 += bf2f(v.w >> 16) * coef;
        }
    }
    // reduce the 4 quarters (same l16 -> same features)
    a0 += __shfl_xor(a0, 16); a0 += __shfl_xor(a0, 32);
    a1 += __shfl_xor(a1, 16); a1 += __shfl_xor(a1, 32);
    a2 += __shfl_xor(a2, 16); a2 += __shfl_xor(a2, 32);
    a3 += __shfl_xor(a3, 16); a3 += __shfl_xor(a3, 32);
    a4 += __shfl_xor(a4, 16); a4 += __shfl_xor(a4, 32);
    a5 += __shfl_xor(a5, 16); a5 += __shfl_xor(a5, 32);
    a6 += __shfl_xor(a6, 16); a6 += __shfl_xor(a6, 32);
    a7 += __shfl_xor(a7, 16); a7 += __shfl_xor(a7, 32);

    uint4 sv = h4[(size_t)i * 16 + l16];
    float4 bv0 = ((const float4*)b)[l16 * 2];
    float4 bv1 = ((const float4*)b)[l16 * 2 + 1];
    float dd = di * di;
    float v0 = a0 + bf2f(sv.x & 0xffffu) * dd + bv0.x;
    float v1 = a1 + bf2f(sv.x >> 16) * dd + bv0.y;
    float v2 = a2 + bf2f(sv.y & 0xffffu) * dd + bv0.z;
    float v3 = a3 + bf2f(sv.y >> 16) * dd + bv0.w;
    float v4 = a4 + bf2f(sv.z & 0xffffu) * dd + bv1.x;
    float v5 = a5 + bf2f(sv.z >> 16) * dd + bv1.y;
    float v6 = a6 + bf2f(sv.w & 0xffffu) * dd + bv1.z;
    float v7 = a7 + bf2f(sv.w >> 16) * dd + bv1.w;
    v0 = (v0 >= 0.f) ? v0 : NEG * v0;
    v1 = (v1 >= 0.f) ? v1 : NEG * v1;
    v2 = (v2 >= 0.f) ? v2 : NEG * v2;
    v3 = (v3 >= 0.f) ? v3 : NEG * v3;
    v4 = (v4 >= 0.f) ? v4 : NEG * v4;
    v5 = (v5 >= 0.f) ? v5 : NEG * v5;
    v6 = (v6 >= 0.f) ? v6 : NEG * v6;
    v7 = (v7 >= 0.f) ? v7 : NEG * v7;
    if (q == 0) {
        uint4 pv;
        pv.x = (unsigned int)f2bf(v0) | ((unsigned int)f2bf(v1) << 16);
        pv.y = (unsigned int)f2bf(v2) | ((unsigned int)f2bf(v3) << 16);
        pv.z = (unsigned int)f2bf(v4) | ((unsigned int)f2bf(v5) << 16);
        pv.w = (unsigned int)f2bf(v6) | ((unsigned int)f2bf(v7) << 16);
        out4[(size_t)i * 16 + l16] = pv;
    }
}

// ---------------- pool: zero sums ----------------
__global__ void zero_pool_kernel(float* __restrict__ pooled) {
    pooled[blockIdx.x * 256 + threadIdx.x] = 0.f;
}

// ---------------- pool: node-parallel chunked accumulate (batch sorted) ----------------
#define PROWS 128
__global__ void pool_accum_kernel(const unsigned int* __restrict__ a2,
                                  const int* __restrict__ batch,
                                  float* __restrict__ pooled, int N) {
    int wave = threadIdx.x >> 6;
    int lane = threadIdx.x & 63;
    int start = blockIdx.x * PROWS;
    int end = start + PROWS;
    if (end > N) end = N;
    float s0 = 0.f, s1 = 0.f;
    int curg = -1;
    for (int r = start + wave; r < end; r += 4) {
        int g = batch[r];                    // wave-uniform branch (sorted batch)
        if (g != curg) {
            if (curg >= 0) {
                atomicAdd(&pooled[curg * D + 2 * lane], s0);
                atomicAdd(&pooled[curg * D + 2 * lane + 1], s1);
            }
            curg = g;
            s0 = 0.f;
            s1 = 0.f;
        }
        unsigned int v = a2[(size_t)r * 64 + lane];
        s0 += bf2f(v & 0xffffu);
        s1 += bf2f(v >> 16);
    }
    if (curg >= 0) {
        atomicAdd(&pooled[curg * D + 2 * lane], s0);
        atomicAdd(&pooled[curg * D + 2 * lane + 1], s1);
    }
}

// ---------------- final linear: out[g,c] = (sum[g]/cnt[g]) . Wl[:,c] + bl[c] ----------------
__global__ void final_kernel(const float* __restrict__ pooled, const int* __restrict__ batch,
                             const float* __restrict__ Wl, const float* __restrict__ bl,
                             float* __restrict__ out, int N) {
    int t = blockIdx.x * blockDim.x + threadIdx.x;
    if (t >= NG * NC) return;
    int g = t >> 4, c = t & 15;
    int l = 0, h = N;
    while (l < h) { int m = (l + h) >> 1; if (batch[m] < g) l = m + 1; else h = m; }
    int lo = l;
    h = N;
    while (l < h) { int m = (l + h) >> 1; if (batch[m] < g + 1) l = m + 1; else h = m; }
    int cnt = l - lo;
    float inv = 1.0f / (float)(cnt > 0 ? cnt : 1);
    float dot = 0.f;
    for (int k = 0; k < D; k++) dot += pooled[g * D + k] * Wl[k * NC + c];
    out[t] = dot * inv + bl[c];
}

extern "C" void kernel_launch(void* const* d_in, const int* in_sizes, int n_in,
                              void* d_out, int out_size, void* d_ws, size_t ws_size,
                              hipStream_t stream) {
    const float* x = (const float*)d_in[0];
    const int* ei = (const int*)d_in[1];
    const int* batch = (const int*)d_in[2];
    const float* W1 = (const float*)d_in[3];
    const float* b1 = (const float*)d_in[4];
    const float* W2 = (const float*)d_in[5];
    const float* b2 = (const float*)d_in[6];
    const float* Wlin = (const float*)d_in[7];
    const float* bl = (const float*)d_in[8];
    float* out = (float*)d_out;

    int N = in_sizes[0] / D;
    int E = in_sizes[1] / 2;
    const int* src = ei;
    const int* dst = ei + E;

    // workspace layout (float units; intermediates are packed-bf16)
    float* ws = (float*)d_ws;
    size_t o = 0;
    unsigned int* bufA = (unsigned int*)(ws + o); o += (size_t)N * 64;  // 12.8 MB
    unsigned int* bufB = (unsigned int*)(ws + o); o += (size_t)N * 64;  // 12.8 MB
    int* deg = (int*)(ws + o);      o += N;       // zeroed below
    int* fill = (int*)(ws + o);     o += N;       // zeroed below (adjacent to deg)
    float* dinv = ws + o;           o += N;
    int* scan1 = (int*)(ws + o);    o += N;
    int* blocksum = (int*)(ws + o); o += 256;
    int* blockoff = (int*)(ws + o); o += 256;
    int* csr_ptr = (int*)(ws + o);  o += (N + 4);
    int* csr_src = (int*)(ws + o);  o += E;
    float* pooled = ws + o;         o += NG * D;

    hipMemsetAsync(deg, 0, (size_t)2 * N * sizeof(int), stream);  // deg + fill

    int tb = 256;
    int nscan = (N + 255) / 256;
    deg_kernel<<<(E + tb - 1) / tb, tb, 0, stream>>>(dst, deg, E);
    dinv_kernel<<<(N + tb - 1) / tb, tb, 0, stream>>>(deg, dinv, N);
    scan_block_kernel<<<nscan, 256, 0, stream>>>(deg, scan1, blocksum, N);
    scan_tops_kernel<<<1, 256, 0, stream>>>(blocksum, blockoff, nscan);
    finalize_ptr_kernel<<<nscan, 256, 0, stream>>>(deg, scan1, blockoff, csr_ptr, N, E);
    scatter_kernel<<<(E + tb - 1) / tb, tb, 0, stream>>>(src, dst, csr_ptr, fill, csr_src, E);

    int gblocks = (N + 63) / 64;
    int cblocks = (N + 3) / 4;
    // layer 1
    gemm_f32_kernel<<<gblocks, 256, 0, stream>>>(x, W1, bufA, N);
    combine_kernel<<<cblocks, 256, 0, stream>>>((const uint4*)bufA, csr_ptr, csr_src, dinv, b1,
                                                (uint4*)bufB, N);
    // layer 2
    gemm_bf16_kernel<<<gblocks, 256, 0, stream>>>(bufB, W2, bufA, N);
    combine_kernel<<<cblocks, 256, 0, stream>>>((const uint4*)bufA, csr_ptr, csr_src, dinv, b2,
                                                (uint4*)bufB, N);
    // pool + classifier
    zero_pool_kernel<<<(NG * D) / 256, 256, 0, stream>>>(pooled);
    pool_accum_kernel<<<(N + PROWS - 1) / PROWS, 256, 0, stream>>>(bufB, batch, pooled, N);
    final_kernel<<<(NG * NC + tb - 1) / tb, tb, 0, stream>>>(pooled, batch, Wlin, bl, out, N);
}

// Round 6
// 268.167 us; speedup vs baseline: 1.5208x; 1.1359x over previous
//
#include <hip/hip_runtime.h>

#define D 128
#define NG 64
#define NC 16
#define NEG 0.1f

typedef __attribute__((ext_vector_type(8))) short bf16x8;
typedef __attribute__((ext_vector_type(4))) float f32x4;

// ---------- bf16 <-> fp32 helpers (bf16 stored as ushort, packed pairs in uint) ----------
__device__ __forceinline__ float bf2f(unsigned int u16) {
    union { unsigned int i; float f; } c;
    c.i = u16 << 16;
    return c.f;
}
__device__ __forceinline__ unsigned short f2bf(float f) {
    union { float f; unsigned int i; } c;
    c.f = f;
    unsigned int i = c.i;
    unsigned int r = (i + 0x7FFFu + ((i >> 16) & 1u)) >> 16;  // RNE
    return (unsigned short)r;
}

// ---------------- degree histogram ----------------
__global__ void deg_kernel(const int* __restrict__ dst, int* __restrict__ deg, int E) {
    int e = blockIdx.x * blockDim.x + threadIdx.x;
    if (e < E) atomicAdd(&deg[dst[e]], 1);
}

// ---------------- W precast, split precision: W ~= Wh + Wl (both bf16, transposed) ----------------
__global__ void prep_w_kernel(const float* __restrict__ W, unsigned short* __restrict__ Wh,
                              unsigned short* __restrict__ Wl) {
    int idx = blockIdx.x * 256 + threadIdx.x;  // 16384
    int k = idx >> 7, n = idx & 127;
    float x = W[idx];
    unsigned short hi = f2bf(x);
    unsigned short lo = f2bf(x - bf2f(hi));
    Wh[n * 128 + k] = hi;
    Wl[n * 128 + k] = lo;
}

// ---------------- scan stage 1 (+ dinv fold) ----------------
__global__ void scan_block_kernel(const int* __restrict__ deg, int* __restrict__ scan1,
                                  int* __restrict__ blocksum, float* __restrict__ dinv, int N) {
    __shared__ int sm[256];
    int tid = threadIdx.x;
    int i = blockIdx.x * 256 + tid;
    int v = (i < N) ? deg[i] : 0;
    if (i < N) dinv[i] = 1.0f / sqrtf((float)v + 1.0f);
    sm[tid] = v;
    __syncthreads();
    for (int off = 1; off < 256; off <<= 1) {
        int t = (tid >= off) ? sm[tid - off] : 0;
        __syncthreads();
        sm[tid] += t;
        __syncthreads();
    }
    if (i < N) scan1[i] = sm[tid];  // inclusive
    if (tid == 255) blocksum[blockIdx.x] = sm[255];
}

__global__ void scan_tops_kernel(const int* __restrict__ blocksum, int* __restrict__ blockoff,
                                 int nb) {
    __shared__ int sm[256];
    int tid = threadIdx.x;
    int v = (tid < nb) ? blocksum[tid] : 0;
    sm[tid] = v;
    __syncthreads();
    for (int off = 1; off < 256; off <<= 1) {
        int t = (tid >= off) ? sm[tid - off] : 0;
        __syncthreads();
        sm[tid] += t;
        __syncthreads();
    }
    blockoff[tid] = sm[tid] - v;  // exclusive
}

__global__ void finalize_ptr_kernel(const int* __restrict__ deg, const int* __restrict__ scan1,
                                    const int* __restrict__ blockoff, int* __restrict__ ptr,
                                    int N, int E) {
    int i = blockIdx.x * blockDim.x + threadIdx.x;
    if (i < N) {
        ptr[i] = scan1[i] - deg[i] + blockoff[i >> 8];  // exclusive prefix
        if (i == N - 1) ptr[N] = E;
    }
}

// ---------------- scatter edges into CSR by dst (+ per-edge coef) ----------------
__global__ void scatter_kernel(const int* __restrict__ src, const int* __restrict__ dst,
                               const int* __restrict__ ptr, int* __restrict__ fill,
                               const float* __restrict__ dinv,
                               int* __restrict__ csr_src, float* __restrict__ csr_coef, int E) {
    int e = blockIdx.x * blockDim.x + threadIdx.x;
    if (e < E) {
        int d = dst[e];
        int s = src[e];
        int pos = ptr[d] + atomicAdd(&fill[d], 1);
        csr_src[pos] = s;
        csr_coef[pos] = dinv[s] * dinv[d];
    }
}

// ---------------- MFMA GEMM: C[N,128](packed bf16) = A[N,128] @ (Wh+Wl) ----------------
// 256 thr (4 waves), 64 rows/block. A fragments straight from global (each element read once).
// LDS: only W^T hi+lo (split precision). Epilogue: shfl-pack bf16 pairs, direct global store.
template <bool AF32>
__global__ __launch_bounds__(256) void gemm_mfma_kernel(const void* __restrict__ Ap,
                                                        const unsigned short* __restrict__ Wh,
                                                        const unsigned short* __restrict__ Wl,
                                                        unsigned int* __restrict__ C, int N) {
    __shared__ unsigned short WsH[128 * 136];  // 34816 B
    __shared__ unsigned short WsL[128 * 136];  // 34816 B
    int tid = threadIdx.x;
    int w = tid >> 6, lane = tid & 63;
    int quad = lane >> 4, m = lane & 15;
    int rowstart = blockIdx.x * 64;

    // stage W^T hi+lo (rows = n, 16 uint4 each, pad to 17)
    {
        const uint4* GH = (const uint4*)Wh;
        const uint4* GL = (const uint4*)Wl;
        uint4* LH = (uint4*)WsH;
        uint4* LL = (uint4*)WsL;
#pragma unroll
        for (int i = 0; i < 8; i++) {
            int li = tid + 256 * i;  // 0..2047
            int r = li >> 4, c = li & 15;
            LH[r * 17 + c] = GH[li];
            LL[r * 17 + c] = GL[li];
        }
    }

    // A fragments from global: row 16w+m, k = kc*32 + quad*8 + j
    int arow = rowstart + 16 * w + m;
    bool valid = arow < N;
    bf16x8 af[4];
    if (AF32) {
        const float* Ag = (const float*)Ap;
#pragma unroll
        for (int kc = 0; kc < 4; kc++) {
            float4 f0 = make_float4(0.f, 0.f, 0.f, 0.f), f1 = f0;
            if (valid) {
                const float4* p = (const float4*)(Ag + (size_t)arow * 128 + kc * 32 + quad * 8);
                f0 = p[0];
                f1 = p[1];
            }
            bf16x8 a;
            a[0] = (short)f2bf(f0.x); a[1] = (short)f2bf(f0.y);
            a[2] = (short)f2bf(f0.z); a[3] = (short)f2bf(f0.w);
            a[4] = (short)f2bf(f1.x); a[5] = (short)f2bf(f1.y);
            a[6] = (short)f2bf(f1.z); a[7] = (short)f2bf(f1.w);
            af[kc] = a;
        }
    } else {
        const unsigned short* Ag = (const unsigned short*)Ap;
#pragma unroll
        for (int kc = 0; kc < 4; kc++) {
            bf16x8 a;
#pragma unroll
            for (int j = 0; j < 8; j++) a[j] = 0;
            if (valid) a = *(const bf16x8*)(Ag + (size_t)arow * 128 + kc * 32 + quad * 8);
            af[kc] = a;
        }
    }
    __syncthreads();

    f32x4 acc[8];
#pragma unroll
    for (int t = 0; t < 8; t++) acc[t] = (f32x4){0.f, 0.f, 0.f, 0.f};

#pragma unroll
    for (int t = 0; t < 8; t++) {
#pragma unroll
        for (int kc = 0; kc < 4; kc++) {
            int off = (t * 16 + m) * 136 + kc * 32 + quad * 8;
            bf16x8 bh = *(const bf16x8*)&WsH[off];
            bf16x8 blo = *(const bf16x8*)&WsL[off];
            acc[t] = __builtin_amdgcn_mfma_f32_16x16x32_bf16(af[kc], bh, acc[t], 0, 0, 0);
            acc[t] = __builtin_amdgcn_mfma_f32_16x16x32_bf16(af[kc], blo, acc[t], 0, 0, 0);
        }
    }

    // epilogue: C[row = 16w + quad*4 + r][col = t*16 + m]; pack pairs across m via shfl_xor(1)
#pragma unroll
    for (int t = 0; t < 8; t++) {
#pragma unroll
        for (int r = 0; r < 4; r++) {
            int row = rowstart + 16 * w + quad * 4 + r;
            unsigned int us = f2bf(acc[t][r]);
            unsigned int other = (unsigned int)__shfl_xor((int)us, 1);
            if (((m & 1) == 0) && row < N)
                C[(size_t)row * 64 + t * 8 + (m >> 1)] = us | (other << 16);
        }
    }
}

// ---------------- gather + self-loop + bias + leaky_relu ----------------
// one wave per node; 16 lanes/row (uint4 = 8 feats), 4 rows in flight, 2x unroll.
__global__ void combine_kernel(const uint4* __restrict__ h4, const int* __restrict__ ptr,
                               const int* __restrict__ csr_src, const float* __restrict__ csr_coef,
                               const float* __restrict__ dinv, const float* __restrict__ b,
                               uint4* __restrict__ out4, int N) {
    int wave = threadIdx.x >> 6;
    int lane = threadIdx.x & 63;
    int i = blockIdx.x * 4 + wave;
    if (i >= N) return;
    int q = lane >> 4;
    int l16 = lane & 15;

    int lo = ptr[i], hi = ptr[i + 1];

    float a0 = 0.f, a1 = 0.f, a2 = 0.f, a3 = 0.f, a4 = 0.f, a5 = 0.f, a6 = 0.f, a7 = 0.f;

    int e = lo + q;
    for (; e + 4 < hi; e += 8) {
        int s0 = csr_src[e];  // 16 lanes same addr -> broadcast
        int s1 = csr_src[e + 4];
        float c0 = csr_coef[e];
        float c1 = csr_coef[e + 4];
        uint4 v0 = h4[(size_t)s0 * 16 + l16];
        uint4 v1 = h4[(size_t)s1 * 16 + l16];
        a0 += bf2f(v0.x & 0xffffu) * c0; a1 += bf2f(v0.x >> 16) * c0;
        a2 += bf2f(v0.y & 0xffffu) * c0; a3 += bf2f(v0.y >> 16) * c0;
        a4 += bf2f(v0.z & 0xffffu) * c0; a5 += bf2f(v0.z >> 16) * c0;
        a6 += bf2f(v0.w & 0xffffu) * c0; a7 += bf2f(v0.w >> 16) * c0;
        a0 += bf2f(v1.x & 0xffffu) * c1; a1 += bf2f(v1.x >> 16) * c1;
        a2 += bf2f(v1.y & 0xffffu) * c1; a3 += bf2f(v1.y >> 16) * c1;
        a4 += bf2f(v1.z & 0xffffu) * c1; a5 += bf2f(v1.z >> 16) * c1;
        a6 += bf2f(v1.w & 0xffffu) * c1; a7 += bf2f(v1.w >> 16) * c1;
    }
    if (e < hi) {
        int s0 = csr_src[e];
        float c0 = csr_coef[e];
        uint4 v0 = h4[(size_t)s0 * 16 + l16];
        a0 += bf2f(v0.x & 0xffffu) * c0; a1 += bf2f(v0.x >> 16) * c0;
        a2 += bf2f(v0.y & 0xffffu) * c0; a3 += bf2f(v0.y >> 16) * c0;
        a4 += bf2f(v0.z & 0xffffu) * c0; a5 += bf2f(v0.z >> 16) * c0;
        a6 += bf2f(v0.w & 0xffffu) * c0; a7 += bf2f(v0.w >> 16) * c0;
    }
    // reduce the 4 quarters (same l16 -> same features)
    a0 += __shfl_xor(a0, 16); a0 += __shfl_xor(a0, 32);
    a1 += __shfl_xor(a1, 16); a1 += __shfl_xor(a1, 32);
    a2 += __shfl_xor(a2, 16); a2 += __shfl_xor(a2, 32);
    a3 += __shfl_xor(a3, 16); a3 += __shfl_xor(a3, 32);
    a4 += __shfl_xor(a4, 16); a4 += __shfl_xor(a4, 32);
    a5 += __shfl_xor(a5, 16); a5 += __shfl_xor(a5, 32);
    a6 += __shfl_xor(a6, 16); a6 += __shfl_xor(a6, 32);
    a7 += __shfl_xor(a7, 16); a7 += __shfl_xor(a7, 32);

    float di = dinv[i];
    uint4 sv = h4[(size_t)i * 16 + l16];
    float4 bv0 = ((const float4*)b)[l16 * 2];
    float4 bv1 = ((const float4*)b)[l16 * 2 + 1];
    float dd = di * di;
    float v0 = a0 + bf2f(sv.x & 0xffffu) * dd + bv0.x;
    float v1 = a1 + bf2f(sv.x >> 16) * dd + bv0.y;
    float v2 = a2 + bf2f(sv.y & 0xffffu) * dd + bv0.z;
    float v3 = a3 + bf2f(sv.y >> 16) * dd + bv0.w;
    float v4 = a4 + bf2f(sv.z & 0xffffu) * dd + bv1.x;
    float v5 = a5 + bf2f(sv.z >> 16) * dd + bv1.y;
    float v6 = a6 + bf2f(sv.w & 0xffffu) * dd + bv1.z;
    float v7 = a7 + bf2f(sv.w >> 16) * dd + bv1.w;
    v0 = (v0 >= 0.f) ? v0 : NEG * v0;
    v1 = (v1 >= 0.f) ? v1 : NEG * v1;
    v2 = (v2 >= 0.f) ? v2 : NEG * v2;
    v3 = (v3 >= 0.f) ? v3 : NEG * v3;
    v4 = (v4 >= 0.f) ? v4 : NEG * v4;
    v5 = (v5 >= 0.f) ? v5 : NEG * v5;
    v6 = (v6 >= 0.f) ? v6 : NEG * v6;
    v7 = (v7 >= 0.f) ? v7 : NEG * v7;
    if (q == 0) {
        uint4 pv;
        pv.x = (unsigned int)f2bf(v0) | ((unsigned int)f2bf(v1) << 16);
        pv.y = (unsigned int)f2bf(v2) | ((unsigned int)f2bf(v3) << 16);
        pv.z = (unsigned int)f2bf(v4) | ((unsigned int)f2bf(v5) << 16);
        pv.w = (unsigned int)f2bf(v6) | ((unsigned int)f2bf(v7) << 16);
        out4[(size_t)i * 16 + l16] = pv;
    }
}

// ---------------- pool: zero sums ----------------
__global__ void zero_pool_kernel(float* __restrict__ pooled) {
    pooled[blockIdx.x * 256 + threadIdx.x] = 0.f;
}

// ---------------- pool: node-parallel chunked accumulate (batch sorted) ----------------
#define PROWS 128
__global__ void pool_accum_kernel(const unsigned int* __restrict__ a2,
                                  const int* __restrict__ batch,
                                  float* __restrict__ pooled, int N) {
    int wave = threadIdx.x >> 6;
    int lane = threadIdx.x & 63;
    int start = blockIdx.x * PROWS;
    int end = start + PROWS;
    if (end > N) end = N;
    float s0 = 0.f, s1 = 0.f;
    int curg = -1;
    for (int r = start + wave; r < end; r += 4) {
        int g = batch[r];  // wave-uniform (sorted batch)
        if (g != curg) {
            if (curg >= 0) {
                atomicAdd(&pooled[curg * D + 2 * lane], s0);
                atomicAdd(&pooled[curg * D + 2 * lane + 1], s1);
            }
            curg = g;
            s0 = 0.f;
            s1 = 0.f;
        }
        unsigned int v = a2[(size_t)r * 64 + lane];
        s0 += bf2f(v & 0xffffu);
        s1 += bf2f(v >> 16);
    }
    if (curg >= 0) {
        atomicAdd(&pooled[curg * D + 2 * lane], s0);
        atomicAdd(&pooled[curg * D + 2 * lane + 1], s1);
    }
}

// ---------------- final linear: out[g,c] = (sum[g]/cnt[g]) . Wl[:,c] + bl[c] ----------------
__global__ void final_kernel(const float* __restrict__ pooled, const int* __restrict__ batch,
                             const float* __restrict__ Wl, const float* __restrict__ bl,
                             float* __restrict__ out, int N) {
    int t = blockIdx.x * blockDim.x + threadIdx.x;
    if (t >= NG * NC) return;
    int g = t >> 4, c = t & 15;
    int l = 0, h = N;
    while (l < h) { int m = (l + h) >> 1; if (batch[m] < g) l = m + 1; else h = m; }
    int lo = l;
    h = N;
    while (l < h) { int m = (l + h) >> 1; if (batch[m] < g + 1) l = m + 1; else h = m; }
    int cnt = l - lo;
    float inv = 1.0f / (float)(cnt > 0 ? cnt : 1);
    float dot = 0.f;
    for (int k = 0; k < D; k++) dot += pooled[g * D + k] * Wl[k * NC + c];
    out[t] = dot * inv + bl[c];
}

extern "C" void kernel_launch(void* const* d_in, const int* in_sizes, int n_in,
                              void* d_out, int out_size, void* d_ws, size_t ws_size,
                              hipStream_t stream) {
    const float* x = (const float*)d_in[0];
    const int* ei = (const int*)d_in[1];
    const int* batch = (const int*)d_in[2];
    const float* W1 = (const float*)d_in[3];
    const float* b1 = (const float*)d_in[4];
    const float* W2 = (const float*)d_in[5];
    const float* b2 = (const float*)d_in[6];
    const float* Wlin = (const float*)d_in[7];
    const float* bl = (const float*)d_in[8];
    float* out = (float*)d_out;

    int N = in_sizes[0] / D;
    int E = in_sizes[1] / 2;
    const int* src = ei;
    const int* dst = ei + E;

    // workspace layout (float units). NOTE: each 128x128 bf16 array = 16384 shorts = 8192 floats.
    float* ws = (float*)d_ws;
    size_t o = 0;
    unsigned int* bufA = (unsigned int*)(ws + o); o += (size_t)N * 64;  // 12.8 MB
    unsigned int* bufB = (unsigned int*)(ws + o); o += (size_t)N * 64;  // 12.8 MB
    int* deg = (int*)(ws + o);      o += N;       // zeroed below
    int* fill = (int*)(ws + o);     o += N;       // zeroed below (adjacent to deg)
    float* dinv = ws + o;           o += N;
    int* scan1 = (int*)(ws + o);    o += N;
    int* blocksum = (int*)(ws + o); o += 256;
    int* blockoff = (int*)(ws + o); o += 256;
    int* csr_ptr = (int*)(ws + o);  o += (N + 4);
    int* csr_src = (int*)(ws + o);  o += E;
    float* csr_coef = ws + o;       o += E;
    float* pooled = ws + o;         o += NG * D;
    unsigned short* Wt1h = (unsigned short*)(ws + o); o += 8192;
    unsigned short* Wt1l = (unsigned short*)(ws + o); o += 8192;
    unsigned short* Wt2h = (unsigned short*)(ws + o); o += 8192;
    unsigned short* Wt2l = (unsigned short*)(ws + o); o += 8192;

    hipMemsetAsync(deg, 0, (size_t)2 * N * sizeof(int), stream);  // deg + fill

    int tb = 256;
    int nscan = (N + 255) / 256;
    prep_w_kernel<<<64, 256, 0, stream>>>(W1, Wt1h, Wt1l);
    prep_w_kernel<<<64, 256, 0, stream>>>(W2, Wt2h, Wt2l);
    deg_kernel<<<(E + tb - 1) / tb, tb, 0, stream>>>(dst, deg, E);
    scan_block_kernel<<<nscan, 256, 0, stream>>>(deg, scan1, blocksum, dinv, N);
    scan_tops_kernel<<<1, 256, 0, stream>>>(blocksum, blockoff, nscan);
    finalize_ptr_kernel<<<nscan, 256, 0, stream>>>(deg, scan1, blockoff, csr_ptr, N, E);
    scatter_kernel<<<(E + tb - 1) / tb, tb, 0, stream>>>(src, dst, csr_ptr, fill, dinv,
                                                         csr_src, csr_coef, E);

    int gblocks = (N + 63) / 64;
    int cblocks = (N + 3) / 4;
    // layer 1
    gemm_mfma_kernel<true><<<gblocks, 256, 0, stream>>>(x, Wt1h, Wt1l, (unsigned int*)bufA, N);
    combine_kernel<<<cblocks, 256, 0, stream>>>((const uint4*)bufA, csr_ptr, csr_src, csr_coef,
                                                dinv, b1, (uint4*)bufB, N);
    // layer 2
    gemm_mfma_kernel<false><<<gblocks, 256, 0, stream>>>(bufB, Wt2h, Wt2l, (unsigned int*)bufA, N);
    combine_kernel<<<cblocks, 256, 0, stream>>>((const uint4*)bufA, csr_ptr, csr_src, csr_coef,
                                                dinv, b2, (uint4*)bufB, N);
    // pool + classifier
    zero_pool_kernel<<<(NG * D) / 256, 256, 0, stream>>>(pooled);
    pool_accum_kernel<<<(N + PROWS - 1) / PROWS, 256, 0, stream>>>(bufB, batch, pooled, N);
    final_kernel<<<(NG * NC + tb - 1) / tb, tb, 0, stream>>>(pooled, batch, Wlin, bl, out, N);
}